// Round 9
// baseline (97308.258 us; speedup 1.0000x reference)
//
#include <hip/hip_runtime.h>
#include <cstdint>
#include <cstddef>

#define HS 512

constexpr int TPB  = 512;            // 8 waves/block
constexpr int GBLK = 64;
constexpr int OWNB = 24;             // owned carry rows per block (groups 8..31)

// combined pub record (u64 tagged slots), per parity:
//   [0,1536)        x      (q-indexed h')
//   [1536,8192)     grp/wp logit partials: slot 1536 + r*64 + b   (r=0..103)
//   [8192,9216)     c values: ca col -> 8192+col, cm col -> 8704+col
//   [9216,9316)     gwpa logits (complete, incl bias+pre)
//   [9316,9416)     gwpm logits
constexpr int PUBN = 9416;

// ---------------- workspace layout (float offsets) ----------------
constexpr size_t OFF_TWwpa = 0;                       // [100][512]
constexpr size_t OFF_TWwpm = OFF_TWwpa + 100*512;
constexpr size_t OFF_TWca  = OFF_TWwpm + 100*512;     // [512][512]
constexpr size_t OFF_TWcm  = OFF_TWca  + 512*512;
constexpr size_t OFF_TWh0  = OFF_TWcm  + 512*512;     // W_rh[512:1024)^T   (h)
constexpr size_t OFF_TWh1  = OFF_TWh0  + 512*512;     // W_rha[2560:3072)^T (ha)
constexpr size_t OFF_TWh2  = OFF_TWh1  + 512*512;     // W_rhm[2560:3072)^T (hm)
constexpr size_t OFF_TWu0  = OFF_TWh2  + 512*512;     // W_rh[0:512)^T      (r)
constexpr size_t OFF_TWu1  = OFF_TWu0  + 512*512;     // W_rha[2048:2560)^T
constexpr size_t OFF_TWu2  = OFF_TWu1  + 512*512;     // W_rhm[2048:2560)^T
constexpr size_t OFF_PAca  = OFF_TWu2  + 512*512;     // [4096][512]
constexpr size_t OFF_PMcm  = OFF_PAca  + 4096*512;
constexpr size_t OFF_PArha = OFF_PMcm  + 4096*512;
constexpr size_t OFF_PMrhm = OFF_PArha + 4096*512;
constexpr size_t OFF_PAwpa = OFF_PMrhm + 4096*512;    // [4096][100]
constexpr size_t OFF_PMwpm = OFF_PAwpa + 4096*100;
constexpr size_t OFF_PUB   = OFF_PMwpm + 4096*100;    // u64[2][PUBN]

// ---------------- LDS blob layout (float offsets) ----------------
constexpr int LX   = 0;               // 1536: [ha|hm|h]
constexpr int LPP  = 1536;            // 104 rows x 68 pad
constexpr int LCC  = LPP + 104*68;    // 1024: [ca|cm]          = 8608
constexpr int LLA  = LCC + 1024;      // 100 (+4 pad)           = 9632
constexpr int LLM  = LLA + 104;       // 100 (+4)               = 9736
constexpr int LAR  = LLM + 104;       // 112                    = 9840
constexpr int LAWA = LAR + 112;       //                        = 9952
constexpr int LAWM = LAWA + 112;      //                        = 10064
constexpr int LAW  = LAWM + 112;      // 8: DOUBLE-BUFFERED aw  = 10176
constexpr int LHN  = LAW + 8;         // 24                     = 10184
constexpr int LTOT = 10208;

// ---------------- device helpers ----------------
__device__ __forceinline__ unsigned long long ald(const unsigned long long* p) {
  return __hip_atomic_load(const_cast<unsigned long long*>(p),
                           __ATOMIC_RELAXED, __HIP_MEMORY_SCOPE_AGENT);
}
__device__ __forceinline__ void gstTag(unsigned long long* p, float v, unsigned tag) {
  unsigned long long u = ((unsigned long long)tag << 32) | (unsigned long long)__float_as_uint(v);
  __hip_atomic_store(p, u, __ATOMIC_RELAXED, __HIP_MEMORY_SCOPE_AGENT);
}
__device__ __forceinline__ float rsum16(float v) {
  #pragma unroll
  for (int o = 8; o; o >>= 1) v += __shfl_xor(v, o, 64);
  return v;
}

// ---------------- prep kernels ----------------
__global__ void initK(unsigned long long* pub) {
  int i = blockIdx.x * blockDim.x + threadIdx.x, st = gridDim.x * blockDim.x;
  for (int k = i; k < PUBN; k += st) pub[k] = (1ull << 32);   // parity0: val 0, tag 1
  for (int k = i; k < PUBN; k += st) pub[PUBN + k] = 0ull;
}

__global__ void transK(const float* __restrict__ src, float* __restrict__ dst, int R, int C) {
  __shared__ float tile[32][33];
  int c0 = blockIdx.x * 32, r0 = blockIdx.y * 32;
  for (int i = threadIdx.y; i < 32; i += 8) {
    int r = r0 + i, c = c0 + threadIdx.x;
    tile[i][threadIdx.x] = (r < R && c < C) ? src[(size_t)r * C + c] : 0.f;
  }
  __syncthreads();
  for (int i = threadIdx.y; i < 32; i += 8) {
    int c = c0 + i, r = r0 + threadIdx.x;
    if (c < C && r < R) dst[(size_t)c * R + r] = tile[threadIdx.x][i];
  }
}

__global__ __launch_bounds__(256) void gemmK(const float* __restrict__ X,
                                             const float* __restrict__ W,
                                             float* __restrict__ C, int N) {
  __shared__ float As[16][68];
  __shared__ float Bs[16][68];
  int t0 = blockIdx.y * 64, n0 = blockIdx.x * 64;
  int tid = threadIdx.x, tx = tid & 15, ty = tid >> 4;
  float acc[4][4] = {};
  for (int k0 = 0; k0 < 2048; k0 += 16) {
    {
      int r = tid >> 2, c = (tid & 3) * 4;
      float4 v = *(const float4*)(X + (size_t)(t0 + r) * 2048 + k0 + c);
      As[c + 0][r] = v.x; As[c + 1][r] = v.y; As[c + 2][r] = v.z; As[c + 3][r] = v.w;
    }
    {
      int kr = tid >> 4, c = (tid & 15) * 4;
      int gcol = n0 + c;
      const float* src = W + (size_t)(k0 + kr) * N + gcol;
      #pragma unroll
      for (int i = 0; i < 4; ++i) Bs[kr][c + i] = (gcol + i < N) ? src[i] : 0.f;
    }
    __syncthreads();
    #pragma unroll
    for (int kk = 0; kk < 16; ++kk) {
      float4 a4 = *(const float4*)&As[kk][ty * 4];
      float4 b4 = *(const float4*)&Bs[kk][tx * 4];
      float av[4] = {a4.x, a4.y, a4.z, a4.w};
      float bv[4] = {b4.x, b4.y, b4.z, b4.w};
      #pragma unroll
      for (int i = 0; i < 4; ++i)
        #pragma unroll
        for (int j = 0; j < 4; ++j) acc[i][j] += av[i] * bv[j];
    }
    __syncthreads();
  }
  #pragma unroll
  for (int i = 0; i < 4; ++i)
    #pragma unroll
    for (int j = 0; j < 4; ++j) {
      int col = n0 + tx * 4 + j;
      if (col < N) C[(size_t)(t0 + ty * 4 + i) * N + col] = acc[i][j];
    }
}

__global__ __launch_bounds__(256) void gemm128(const float* __restrict__ X,
                                               const float* __restrict__ W,
                                               float* __restrict__ C) {
  __shared__ float As[8][132];
  __shared__ float Bs[8][132];
  const int N = 512;
  int t0 = blockIdx.y * 128, n0 = blockIdx.x * 128;
  int tid = threadIdx.x, tx = tid & 15, ty = tid >> 4;
  float acc[8][8] = {};
  for (int k0 = 0; k0 < 2048; k0 += 8) {
    int r = tid >> 1, c4 = (tid & 1) * 4;
    float4 va = *(const float4*)(X + (size_t)(t0 + r) * 2048 + k0 + c4);
    int kr = tid >> 5, cb = (tid & 31) * 4;
    float4 vb = *(const float4*)(W + (size_t)(k0 + kr) * N + n0 + cb);
    __syncthreads();
    As[c4 + 0][r] = va.x; As[c4 + 1][r] = va.y; As[c4 + 2][r] = va.z; As[c4 + 3][r] = va.w;
    Bs[kr][cb] = vb.x; Bs[kr][cb + 1] = vb.y; Bs[kr][cb + 2] = vb.z; Bs[kr][cb + 3] = vb.w;
    __syncthreads();
    #pragma unroll
    for (int kk = 0; kk < 8; ++kk) {
      float av[8], bv[8];
      *(float4*)av       = *(const float4*)&As[kk][ty * 8];
      *(float4*)(av + 4) = *(const float4*)&As[kk][ty * 8 + 4];
      *(float4*)bv       = *(const float4*)&Bs[kk][tx * 8];
      *(float4*)(bv + 4) = *(const float4*)&Bs[kk][tx * 8 + 4];
      #pragma unroll
      for (int i = 0; i < 8; ++i)
        #pragma unroll
        for (int j = 0; j < 8; ++j) acc[i][j] += av[i] * bv[j];
    }
  }
  #pragma unroll
  for (int i = 0; i < 8; ++i) {
    float* dst = C + (size_t)(t0 + ty * 8 + i) * N + n0 + tx * 8;
    *(float4*)dst       = *(float4*)&acc[i][0];
    *(float4*)(dst + 4) = *(float4*)&acc[i][4];
  }
}

// ---------------- persistent recurrence kernel ----------------
struct RArgs {
  const float *Wrp, *Wwp;                                   // raw, for partial cols
  const float *TWwpa, *TWwpm, *TWca, *TWcm;
  const float *TWh0, *TWh1, *TWh2, *TWu0, *TWu1, *TWu2;
  const float *PAca, *PMcm, *PArha, *PMrhm, *PAwpa, *PMwpm;
  const float *b_ca, *b_cm, *b_wp, *b_wpa, *b_wpm, *b_rp, *b_rh, *b_rha, *b_rhm;
  unsigned long long *pub;
  float *out;
  int nT;
};

__global__ __launch_bounds__(TPB, 1) void recurK(RArgs a) {
  const int tid  = threadIdx.x;
  const int lane = tid & 63;
  const int lw   = tid >> 6;                 // wave 0..7
  const int g    = tid >> 4;                 // 16-lane group 0..31
  const int gl   = tid & 15;
  const int b    = blockIdx.x;

  __shared__ __align__(16) float Bf[LTOT];   // ~40 KB blob

  // ---- static assignment maps ----
  const int r0a = (b + 51) & 63;             // gwpa rows r0a, r0a+64(if<36)
  const int r1m = (b + 25) & 63;             // gwpm rows

  for (int i = tid; i < LTOT; i += TPB) Bf[i] = 0.f;

  // ---- roles ----
  // phase A' (post-SYNC2 publish): groups 0-7 ca cols, 8-15 cm cols, 16-19 gates
  int slotA = -1, xoffA = 0, strideA = 512;
  bool reluA = false;
  float biasA = 0.f;
  const float* preAPtr = nullptr;
  const float* wARow = nullptr;
  if (g < 8) {
    int col = b * 8 + g;
    slotA = 8192 + col; reluA = true; biasA = a.b_ca[col]; preAPtr = a.PAca + col;
    wARow = a.TWca + (size_t)col * 512; xoffA = LX;
  } else if (g < 16) {
    int col = b * 8 + (g - 8);
    slotA = 8704 + col; reluA = true; biasA = a.b_cm[col]; preAPtr = a.PMcm + col;
    wARow = a.TWcm + (size_t)col * 512; xoffA = LX + 512;
  } else if (g < 20) {
    int sl = g - 16;
    strideA = 100;
    if (sl == 0)                  { slotA = 9216 + r0a;      biasA = a.b_wpa[r0a];      preAPtr = a.PAwpa + r0a;      wARow = a.TWwpa + (size_t)r0a * 512;        xoffA = LX;       }
    else if (sl == 1 && r0a < 36) { slotA = 9216 + r0a + 64; biasA = a.b_wpa[r0a + 64]; preAPtr = a.PAwpa + r0a + 64; wARow = a.TWwpa + (size_t)(r0a + 64) * 512; xoffA = LX;       }
    else if (sl == 2)             { slotA = 9316 + r1m;      biasA = a.b_wpm[r1m];      preAPtr = a.PMwpm + r1m;      wARow = a.TWwpm + (size_t)r1m * 512;        xoffA = LX + 512; }
    else if (sl == 3 && r1m < 36) { slotA = 9316 + r1m + 64; biasA = a.b_wpm[r1m + 64]; preAPtr = a.PMwpm + r1m + 64; wARow = a.TWwpm + (size_t)(r1m + 64) * 512; xoffA = LX + 512; }
  }
  // owners: groups 8..31 own q = b*24 + (g-8)
  const bool own = (g >= 8);
  const int rr = g - 8;
  int ownHsel = 0, ownJ = 0, whXo = 0, qOwn = 0;
  float biasO = 0.f;
  const float* preOPtr = nullptr;
  const float* whRow = nullptr;
  const float* uRow = nullptr;
  if (own) {
    qOwn = b * OWNB + rr;
    int hsel = qOwn >> 9, j = qOwn & 511;
    ownHsel = hsel; ownJ = j;
    if (hsel == 0)      { biasO = a.b_rh[j];
                          whRow = a.TWh0 + (size_t)j * 512; whXo = LX + 1024;
                          uRow  = a.TWu0 + (size_t)j * 512; }
    else if (hsel == 1) { biasO = a.b_rha[j]; preOPtr = a.PArha + j;
                          whRow = a.TWh1 + (size_t)j * 512; whXo = LX;
                          uRow  = a.TWu1 + (size_t)j * 512; }
    else                { biasO = a.b_rhm[j]; preOPtr = a.PMrhm + j;
                          whRow = a.TWh2 + (size_t)j * 512; whXo = LX + 512;
                          uRow  = a.TWu2 + (size_t)j * 512; }
  }
  // partial producers: waves 6-7, tid-384 = r (0..103)
  const int rp = tid - 384;
  const bool doPart = (rp >= 0 && rp < 104);

  // ---- register-pinned weights ----
  float4 wA[8], wU[8], wWh[8];
  float  wLb[24];
  float  gr[7];
  #pragma unroll
  for (int it = 0; it < 8; ++it) wA[it] = wU[it] = wWh[it] = make_float4(0.f, 0.f, 0.f, 0.f);
  #pragma unroll
  for (int k = 0; k < 24; ++k) wLb[k] = 0.f;
  #pragma unroll
  for (int k = 0; k < 7; ++k) gr[k] = 0.f;

  if (wARow) {
    const float4* w4 = (const float4*)wARow;
    #pragma unroll
    for (int it = 0; it < 8; ++it) wA[it] = w4[gl + 16 * it];
  }
  if (own) {
    const float4* u4 = (const float4*)uRow;
    const float4* h4 = (const float4*)whRow;
    #pragma unroll
    for (int it = 0; it < 8; ++it) { wU[it] = u4[gl + 16 * it]; wWh[it] = h4[gl + 16 * it]; }
  }
  if (doPart && rp < 103) {
    #pragma unroll
    for (int k = 0; k < 24; ++k) {
      int q = b * OWNB + k;
      int xr = (q < 512) ? 1024 + q : q - 512;
      wLb[k] = (rp < 100) ? a.Wrp[(size_t)xr * 100 + rp]
                          : a.Wwp[(size_t)xr * 3 + (rp - 100)];
    }
  }
  // wave0/3 softmax bias regs
  float bR1 = 0.f, bR2 = 0.f, bW = 0.f;
  if (lw == 0) { bR1 = a.b_rp[lane]; if (lane < 36) bR2 = a.b_rp[64 + lane]; }
  if (lw == 3 && lane < 3) bW = a.b_wp[lane];

  // ---- poll slot table: 19 slots/thread, LDS dst offsets ----
  const int s0 = tid * 19;
  int po[19];
  #pragma unroll
  for (int k = 0; k < 19; ++k) {
    int s = s0 + k;
    int d = -1;
    if (s < 1536) {
      int hs = s >> 9, j = s & 511;
      d = LX + ((hs == 0) ? 1024 : (hs == 1) ? 0 : 512) + j;
    } else if (s < 8192) {
      int u = s - 1536;
      d = LPP + (u >> 6) * 68 + (u & 63);
    } else if (s < 9216) {
      d = LCC + (s - 8192);
    } else if (s < 9316) {
      d = LLA + (s - 9216);
    } else if (s < PUBN) {
      d = LLM + (s - 9316);
    }
    po[k] = d;
  }
  __syncthreads();

  // ---- prologue: pipelined per-step scalars (value for t=0) ----
  float preA_c = preAPtr ? preAPtr[0] : 0.f;
  float preO_c = preOPtr ? preOPtr[0] : 0.f;

  // ---------------- time loop: ONE exchange per step, 3 barriers ----------------
  for (int t = 0; t < a.nT; ++t) {
    const unsigned tagB = (unsigned)t + 1;
    const int par = t & 1;

    // ---- combined poll: x + partials + c + gate logits ----
    {
      const unsigned long long* P = a.pub + (size_t)par * PUBN + s0;
      unsigned long long v[19];
      for (;;) {
        int ok = 1;
        #pragma unroll
        for (int k = 0; k < 19; ++k)
          if (po[k] >= 0) { v[k] = ald(P + k); ok &= ((unsigned)(v[k] >> 32) >= tagB); }
        if (__all(ok)) break;
        __builtin_amdgcn_s_sleep(1);
      }
      #pragma unroll
      for (int k = 0; k < 19; ++k)
        if (po[k] >= 0) Bf[po[k]] = __uint_as_float((unsigned)v[k]);
    }
    __syncthreads();   // SYNC0: all gathered data in LDS

    // issue NEXT step's prefetches (whole step to land)
    const int tn = (t + 1 < a.nT) ? t + 1 : t;
    float preA_n = preAPtr ? preAPtr[(size_t)tn * strideA] : 0.f;
    float preO_n = preOPtr ? preOPtr[(size_t)tn * 512] : 0.f;

    // ---- local compute round (pre-SYNC1) ----
    float whv = 0.f, uA = 0.f, uM = 0.f;
    if (own) {
      const float4* x4 = (const float4*)(Bf + whXo);
      const float4* a4 = (const float4*)(Bf + LCC);
      const float4* m4 = (const float4*)(Bf + LCC + 512);
      float aw_ = 0.f, sa = 0.f, sm = 0.f;
      #pragma unroll
      for (int it = 0; it < 8; ++it) {
        float4 xv = x4[gl + 16 * it];
        aw_ += wWh[it].x * xv.x + wWh[it].y * xv.y + wWh[it].z * xv.z + wWh[it].w * xv.w;
        float4 av = a4[gl + 16 * it], mv = m4[gl + 16 * it];
        sa += wU[it].x * av.x + wU[it].y * av.y + wU[it].z * av.z + wU[it].w * av.w;
        sm += wU[it].x * mv.x + wU[it].y * mv.y + wU[it].z * mv.z + wU[it].w * mv.w;
      }
      whv = rsum16(aw_);
      #pragma unroll
      for (int o = 8; o; o >>= 1) { sa += __shfl_xor(sa, o, 64); sm += __shfl_xor(sm, o, 64); }
      uA = sa; uM = sm;
    }
    if (lw == 0) {          // ar(t): sum partials + bias, softmax
      float x1, x2 = -3.0e38f;
      {
        const float4* r4 = (const float4*)(Bf + LPP + lane * 68);
        float s1 = 0.f;
        #pragma unroll
        for (int k = 0; k < 16; ++k) { float4 q = r4[k]; s1 += q.x + q.y + q.z + q.w; }
        x1 = s1 + bR1;
      }
      if (lane < 36) {
        const float4* r4 = (const float4*)(Bf + LPP + (64 + lane) * 68);
        float s2 = 0.f;
        #pragma unroll
        for (int k = 0; k < 16; ++k) { float4 q = r4[k]; s2 += q.x + q.y + q.z + q.w; }
        x2 = s2 + bR2;
      }
      float m = fmaxf(x1, x2);
      #pragma unroll
      for (int o = 32; o; o >>= 1) m = fmaxf(m, __shfl_xor(m, o, 64));
      float e1 = expf(x1 - m);
      float e2 = (lane < 36) ? expf(x2 - m) : 0.f;
      float ss = e1 + e2;
      #pragma unroll
      for (int o = 32; o; o >>= 1) ss += __shfl_xor(ss, o, 64);
      float inv = 1.f / ss;
      Bf[LAR + lane] = e1 * inv;
      if (lane < 36) Bf[LAR + 64 + lane] = e2 * inv;
    } else if (lw == 1) {   // awa(t-1) from gathered gwpa logits
      bool two = lane < 36;
      float x1 = Bf[LLA + lane];
      float x2 = two ? Bf[LLA + 64 + lane] : -3.0e38f;
      float m = fmaxf(x1, x2);
      #pragma unroll
      for (int o = 32; o; o >>= 1) m = fmaxf(m, __shfl_xor(m, o, 64));
      float e1 = expf(x1 - m);
      float e2 = two ? expf(x2 - m) : 0.f;
      float ss = e1 + e2;
      #pragma unroll
      for (int o = 32; o; o >>= 1) ss += __shfl_xor(ss, o, 64);
      float inv = 1.f / ss;
      Bf[LAWA + lane] = e1 * inv;
      if (two) Bf[LAWA + 64 + lane] = e2 * inv;
    } else if (lw == 2) {   // awm(t-1)
      bool two = lane < 36;
      float x1 = Bf[LLM + lane];
      float x2 = two ? Bf[LLM + 64 + lane] : -3.0e38f;
      float m = fmaxf(x1, x2);
      #pragma unroll
      for (int o = 32; o; o >>= 1) m = fmaxf(m, __shfl_xor(m, o, 64));
      float e1 = expf(x1 - m);
      float e2 = two ? expf(x2 - m) : 0.f;
      float ss = e1 + e2;
      #pragma unroll
      for (int o = 32; o; o >>= 1) ss += __shfl_xor(ss, o, 64);
      float inv = 1.f / ss;
      Bf[LAWM + lane] = e1 * inv;
      if (two) Bf[LAWM + 64 + lane] = e2 * inv;
    } else if (lw == 3) {   // aw(t): wp partial sums + softmax -> slot par
      float x = -3.0e38f;
      if (lane < 3) {
        const float4* r4 = (const float4*)(Bf + LPP + (100 + lane) * 68);
        float s1 = 0.f;
        #pragma unroll
        for (int k = 0; k < 16; ++k) { float4 q = r4[k]; s1 += q.x + q.y + q.z + q.w; }
        x = s1 + bW;
      }
      float m = x;
      #pragma unroll
      for (int o = 32; o; o >>= 1) m = fmaxf(m, __shfl_xor(m, o, 64));
      float e = (lane < 3) ? expf(x - m) : 0.f;
      float ss = e;
      #pragma unroll
      for (int o = 32; o; o >>= 1) ss += __shfl_xor(ss, o, 64);
      if (lane < 3) Bf[LAW + 4 * par + lane] = e / ss;   // aw(t) -> slot par
    }
    __syncthreads();   // SYNC1: ar(t)/awa(t-1)/awm(t-1)/aw(t) ready

    // ---- owners: G update with gates(t-1) -> contrib(t) -> publish h'(t) ----
    unsigned long long* PO = a.pub + (size_t)((t + 1) & 1) * PUBN;
    if (own) {
      // aw(t-1) lives in the OTHER buffer slot (written at step t-1)
      const float aw0 = Bf[LAW + 4 * (par ^ 1) + 0];
      const float aw1 = Bf[LAW + 4 * (par ^ 1) + 1];
      const float aw2 = Bf[LAW + 4 * (par ^ 1) + 2];
      float contrib = 0.f;
      #pragma unroll
      for (int k = 0; k < 7; ++k) {
        int idx = gl + 16 * k;
        gr[k] = aw0 * gr[k] + aw1 * Bf[LAWA + idx] * uA + aw2 * Bf[LAWM + idx] * uM;
        contrib += Bf[LAR + idx] * gr[k];
      }
      contrib = rsum16(contrib);
      if (!gl) {
        float h = fmaxf(contrib + whv + preO_c + biasO, 0.f);
        if (ownHsel == 0) a.out[(size_t)t * 512 + ownJ] = h;
        gstTag(PO + qOwn, h, tagB + 1);
        Bf[LHN + rr] = h;
      }
    }
    __syncthreads();   // SYNC2: s_hnew ready

    // ---- late publish: partials + ca/cm + gate logits (consumed next step) ----
    if (doPart) {
      float p = 0.f;
      #pragma unroll
      for (int k = 0; k < 24; ++k) p += Bf[LHN + k] * wLb[k];
      gstTag(PO + 1536 + rp * 64 + b, p, tagB + 1);
    }
    if (slotA >= 0) {
      const float4* x4 = (const float4*)(Bf + xoffA);
      float acc = 0.f;
      #pragma unroll
      for (int it = 0; it < 8; ++it) {
        float4 xv = x4[gl + 16 * it];
        acc += wA[it].x * xv.x + wA[it].y * xv.y + wA[it].z * xv.z + wA[it].w * xv.w;
      }
      float v = rsum16(acc);
      if (!gl) {
        v += preA_c + biasA;
        if (reluA) v = fmaxf(v, 0.f);
        gstTag(PO + slotA, v, tagB + 1);
      }
    }
    // no barrier here: next poll's exit requires all same-block publishes
    // (poll waits on every slot incl. own block's), which are program-order
    // after all step-t LDS reads -> overwrites at t+1 are safe.

    preA_c = preA_n;
    preO_c = preO_n;
  }
}

// ---------------- host ----------------
extern "C" void kernel_launch(void* const* d_in, const int* in_sizes, int n_in,
                              void* d_out, int out_size, void* d_ws, size_t ws_size,
                              hipStream_t stream) {
  const float* Xa    = (const float*)d_in[0];
  const float* Xm    = (const float*)d_in[1];
  const float* W_ca  = (const float*)d_in[2];  const float* b_ca  = (const float*)d_in[3];
  const float* W_cm  = (const float*)d_in[4];  const float* b_cm  = (const float*)d_in[5];
  const float* W_wp  = (const float*)d_in[6];  const float* b_wp  = (const float*)d_in[7];
  const float* W_wpa = (const float*)d_in[8];  const float* b_wpa = (const float*)d_in[9];
  const float* W_wpm = (const float*)d_in[10]; const float* b_wpm = (const float*)d_in[11];
  const float* W_rp  = (const float*)d_in[12]; const float* b_rp  = (const float*)d_in[13];
  const float* W_rh  = (const float*)d_in[14]; const float* b_rh  = (const float*)d_in[15];
  const float* W_rha = (const float*)d_in[16]; const float* b_rha = (const float*)d_in[17];
  const float* W_rhm = (const float*)d_in[18]; const float* b_rhm = (const float*)d_in[19];

  int nT = out_size / HS;   // 4096
  float* ws = (float*)d_ws;

  initK<<<dim3(64), dim3(256), 0, stream>>>((unsigned long long*)(ws + OFF_PUB));

  dim3 tb(32, 8);
  auto tg = [](int R, int C) { return dim3((C + 31) / 32, (R + 31) / 32); };
  transK<<<tg(512, 100),  tb, 0, stream>>>(W_wpa,                      ws + OFF_TWwpa, 512, 100);
  transK<<<tg(512, 100),  tb, 0, stream>>>(W_wpm,                      ws + OFF_TWwpm, 512, 100);
  transK<<<tg(512, 512),  tb, 0, stream>>>(W_ca,                       ws + OFF_TWca,  512, 512);
  transK<<<tg(512, 512),  tb, 0, stream>>>(W_cm,                       ws + OFF_TWcm,  512, 512);
  transK<<<tg(512, 512),  tb, 0, stream>>>(W_rh  + 512 * 512,          ws + OFF_TWh0,  512, 512);
  transK<<<tg(512, 512),  tb, 0, stream>>>(W_rha + (size_t)2560 * 512, ws + OFF_TWh1,  512, 512);
  transK<<<tg(512, 512),  tb, 0, stream>>>(W_rhm + (size_t)2560 * 512, ws + OFF_TWh2,  512, 512);
  transK<<<tg(512, 512),  tb, 0, stream>>>(W_rh,                       ws + OFF_TWu0,  512, 512);
  transK<<<tg(512, 512),  tb, 0, stream>>>(W_rha + (size_t)2048 * 512, ws + OFF_TWu1,  512, 512);
  transK<<<tg(512, 512),  tb, 0, stream>>>(W_rhm + (size_t)2048 * 512, ws + OFF_TWu2,  512, 512);

  int tB = nT / 128;
  gemm128<<<dim3(4, tB), dim3(256), 0, stream>>>(Xa, W_ca + (size_t)512 * 512, ws + OFF_PAca);
  gemm128<<<dim3(4, tB), dim3(256), 0, stream>>>(Xm, W_cm + (size_t)512 * 512, ws + OFF_PMcm);
  gemm128<<<dim3(4, tB), dim3(256), 0, stream>>>(Xa, W_rha,                    ws + OFF_PArha);
  gemm128<<<dim3(4, tB), dim3(256), 0, stream>>>(Xm, W_rhm,                    ws + OFF_PMrhm);
  int tB64 = nT / 64;
  gemmK<<<dim3(2, tB64), dim3(256), 0, stream>>>(Xa, W_wpa + (size_t)512 * 100, ws + OFF_PAwpa, 100);
  gemmK<<<dim3(2, tB64), dim3(256), 0, stream>>>(Xm, W_wpm + (size_t)512 * 100, ws + OFF_PMwpm, 100);

  RArgs a;
  a.Wrp = W_rp; a.Wwp = W_wp;
  a.TWwpa = ws + OFF_TWwpa; a.TWwpm = ws + OFF_TWwpm;
  a.TWca  = ws + OFF_TWca;  a.TWcm  = ws + OFF_TWcm;
  a.TWh0  = ws + OFF_TWh0;  a.TWh1  = ws + OFF_TWh1;  a.TWh2 = ws + OFF_TWh2;
  a.TWu0  = ws + OFF_TWu0;  a.TWu1  = ws + OFF_TWu1;  a.TWu2 = ws + OFF_TWu2;
  a.PAca  = ws + OFF_PAca;  a.PMcm  = ws + OFF_PMcm;
  a.PArha = ws + OFF_PArha; a.PMrhm = ws + OFF_PMrhm;
  a.PAwpa = ws + OFF_PAwpa; a.PMwpm = ws + OFF_PMwpm;
  a.b_ca = b_ca; a.b_cm = b_cm; a.b_wp = b_wp; a.b_wpa = b_wpa; a.b_wpm = b_wpm;
  a.b_rp = b_rp; a.b_rh = b_rh; a.b_rha = b_rha; a.b_rhm = b_rhm;
  a.pub = (unsigned long long*)(ws + OFF_PUB);
  a.out = (float*)d_out;
  a.nT  = nT;

  recurK<<<dim3(GBLK), dim3(TPB), 0, stream>>>(a);
}

// Round 10
// 27469.785 us; speedup vs baseline: 3.5424x; 3.5424x over previous
//
#include <hip/hip_runtime.h>
#include <cstdint>
#include <cstddef>

#define HS 512

constexpr int TPB  = 512;            // 8 waves/block
constexpr int GBLK = 64;
constexpr int OWNB = 24;             // owned carry rows per block (groups 8..31)

// ---------------- workspace layout (float offsets) ----------------
constexpr size_t OFF_TWrp  = 0;                       // [100][1536]
constexpr size_t OFF_TWwp  = OFF_TWrp  + 100*1536;    // [3][1536]
constexpr size_t OFF_TWwpa = OFF_TWwp  + 3*1536;      // [100][512]
constexpr size_t OFF_TWwpm = OFF_TWwpa + 100*512;
constexpr size_t OFF_TWca  = OFF_TWwpm + 100*512;     // [512][512]
constexpr size_t OFF_TWcm  = OFF_TWca  + 512*512;
constexpr size_t OFF_TWh0  = OFF_TWcm  + 512*512;     // W_rh[512:1024)^T   (h)
constexpr size_t OFF_TWh1  = OFF_TWh0  + 512*512;     // W_rha[2560:3072)^T (ha)
constexpr size_t OFF_TWh2  = OFF_TWh1  + 512*512;     // W_rhm[2560:3072)^T (hm)
constexpr size_t OFF_TWu0  = OFF_TWh2  + 512*512;     // W_rh[0:512)^T      (r)
constexpr size_t OFF_TWu1  = OFF_TWu0  + 512*512;     // W_rha[2048:2560)^T
constexpr size_t OFF_TWu2  = OFF_TWu1  + 512*512;     // W_rhm[2048:2560)^T
constexpr size_t OFF_PAca  = OFF_TWu2  + 512*512;     // [4096][512]
constexpr size_t OFF_PMcm  = OFF_PAca  + 4096*512;
constexpr size_t OFF_PArha = OFF_PMcm  + 4096*512;
constexpr size_t OFF_PMrhm = OFF_PArha + 4096*512;
constexpr size_t OFF_PAwpa = OFF_PMrhm + 4096*512;    // [4096][100]
constexpr size_t OFF_PMwpm = OFF_PAwpa + 4096*100;
constexpr size_t OFF_CARRY = OFF_PMwpm + 4096*100;    // u64[2][1536] tagged
constexpr size_t OFF_BCAST = OFF_CARRY + 2*1536*2;    // u64[2][1344] tagged
// bcast: [0:512) ca  [512:1024) cm  [1024:1124) grp  [1124:1224) gwpa
//        [1224:1324) gwpm  [1324:1327) wp

// ---------------- device helpers ----------------
__device__ __forceinline__ unsigned long long ald(const unsigned long long* p) {
  return __hip_atomic_load(const_cast<unsigned long long*>(p),
                           __ATOMIC_RELAXED, __HIP_MEMORY_SCOPE_AGENT);
}
__device__ __forceinline__ void gstTag(unsigned long long* p, float v, unsigned tag) {
  unsigned long long u = ((unsigned long long)tag << 32) | (unsigned long long)__float_as_uint(v);
  __hip_atomic_store(p, u, __ATOMIC_RELAXED, __HIP_MEMORY_SCOPE_AGENT);
}
__device__ __forceinline__ float xrsum(float v) {
  #pragma unroll
  for (int o = 32; o; o >>= 1) v += __shfl_xor(v, o, 64);
  return v;
}
__device__ __forceinline__ float rsum16(float v) {
  #pragma unroll
  for (int o = 8; o; o >>= 1) v += __shfl_xor(v, o, 64);
  return v;
}

// ---------------- prep kernels ----------------
__global__ void initK(unsigned long long* carryT, unsigned long long* bcast) {
  int i = blockIdx.x * blockDim.x + threadIdx.x, st = gridDim.x * blockDim.x;
  for (int k = i; k < 1536; k += st) carryT[k] = (1ull << 32);   // carry(0)=0, tag 1
  for (int k = i; k < 1536; k += st) carryT[1536 + k] = 0ull;
  for (int k = i; k < 2 * 1344; k += st) bcast[k] = 0ull;
}

__global__ void transK(const float* __restrict__ src, float* __restrict__ dst, int R, int C) {
  __shared__ float tile[32][33];
  int c0 = blockIdx.x * 32, r0 = blockIdx.y * 32;
  for (int i = threadIdx.y; i < 32; i += 8) {
    int r = r0 + i, c = c0 + threadIdx.x;
    tile[i][threadIdx.x] = (r < R && c < C) ? src[(size_t)r * C + c] : 0.f;
  }
  __syncthreads();
  for (int i = threadIdx.y; i < 32; i += 8) {
    int c = c0 + i, r = r0 + threadIdx.x;
    if (c < C && r < R) dst[(size_t)c * R + r] = tile[threadIdx.x][i];
  }
}

__global__ __launch_bounds__(256) void gemmK(const float* __restrict__ X,
                                             const float* __restrict__ W,
                                             float* __restrict__ C, int N) {
  __shared__ float As[16][68];
  __shared__ float Bs[16][68];
  int t0 = blockIdx.y * 64, n0 = blockIdx.x * 64;
  int tid = threadIdx.x, tx = tid & 15, ty = tid >> 4;
  float acc[4][4] = {};
  for (int k0 = 0; k0 < 2048; k0 += 16) {
    {
      int r = tid >> 2, c = (tid & 3) * 4;
      float4 v = *(const float4*)(X + (size_t)(t0 + r) * 2048 + k0 + c);
      As[c + 0][r] = v.x; As[c + 1][r] = v.y; As[c + 2][r] = v.z; As[c + 3][r] = v.w;
    }
    {
      int kr = tid >> 4, c = (tid & 15) * 4;
      int gcol = n0 + c;
      const float* src = W + (size_t)(k0 + kr) * N + gcol;
      #pragma unroll
      for (int i = 0; i < 4; ++i) Bs[kr][c + i] = (gcol + i < N) ? src[i] : 0.f;
    }
    __syncthreads();
    #pragma unroll
    for (int kk = 0; kk < 16; ++kk) {
      float4 a4 = *(const float4*)&As[kk][ty * 4];
      float4 b4 = *(const float4*)&Bs[kk][tx * 4];
      float av[4] = {a4.x, a4.y, a4.z, a4.w};
      float bv[4] = {b4.x, b4.y, b4.z, b4.w};
      #pragma unroll
      for (int i = 0; i < 4; ++i)
        #pragma unroll
        for (int j = 0; j < 4; ++j) acc[i][j] += av[i] * bv[j];
    }
    __syncthreads();
  }
  #pragma unroll
  for (int i = 0; i < 4; ++i)
    #pragma unroll
    for (int j = 0; j < 4; ++j) {
      int col = n0 + tx * 4 + j;
      if (col < N) C[(size_t)(t0 + ty * 4 + i) * N + col] = acc[i][j];
    }
}

__global__ __launch_bounds__(256) void gemm128(const float* __restrict__ X,
                                               const float* __restrict__ W,
                                               float* __restrict__ C) {
  __shared__ float As[8][132];
  __shared__ float Bs[8][132];
  const int N = 512;
  int t0 = blockIdx.y * 128, n0 = blockIdx.x * 128;
  int tid = threadIdx.x, tx = tid & 15, ty = tid >> 4;
  float acc[8][8] = {};
  for (int k0 = 0; k0 < 2048; k0 += 8) {
    int r = tid >> 1, c4 = (tid & 1) * 4;
    float4 va = *(const float4*)(X + (size_t)(t0 + r) * 2048 + k0 + c4);
    int kr = tid >> 5, cb = (tid & 31) * 4;
    float4 vb = *(const float4*)(W + (size_t)(k0 + kr) * N + n0 + cb);
    __syncthreads();
    As[c4 + 0][r] = va.x; As[c4 + 1][r] = va.y; As[c4 + 2][r] = va.z; As[c4 + 3][r] = va.w;
    Bs[kr][cb] = vb.x; Bs[kr][cb + 1] = vb.y; Bs[kr][cb + 2] = vb.z; Bs[kr][cb + 3] = vb.w;
    __syncthreads();
    #pragma unroll
    for (int kk = 0; kk < 8; ++kk) {
      float av[8], bv[8];
      *(float4*)av       = *(const float4*)&As[kk][ty * 8];
      *(float4*)(av + 4) = *(const float4*)&As[kk][ty * 8 + 4];
      *(float4*)bv       = *(const float4*)&Bs[kk][tx * 8];
      *(float4*)(bv + 4) = *(const float4*)&Bs[kk][tx * 8 + 4];
      #pragma unroll
      for (int i = 0; i < 8; ++i)
        #pragma unroll
        for (int j = 0; j < 8; ++j) acc[i][j] += av[i] * bv[j];
    }
  }
  #pragma unroll
  for (int i = 0; i < 8; ++i) {
    float* dst = C + (size_t)(t0 + ty * 8 + i) * N + n0 + tx * 8;
    *(float4*)dst       = *(float4*)&acc[i][0];
    *(float4*)(dst + 4) = *(float4*)&acc[i][4];
  }
}

// ---------------- persistent recurrence kernel ----------------
struct RArgs {
  const float *TWrp, *TWwp, *TWwpa, *TWwpm, *TWca, *TWcm;
  const float *TWh0, *TWh1, *TWh2, *TWu0, *TWu1, *TWu2;
  const float *PAca, *PMcm, *PArha, *PMrhm, *PAwpa, *PMwpm;
  const float *b_ca, *b_cm, *b_wp, *b_wpa, *b_wpm, *b_rp, *b_rh, *b_rha, *b_rhm;
  unsigned long long *carryT, *bcast;
  float *out;
  int nT;
};

__global__ __launch_bounds__(TPB, 1) void recurK(RArgs a) {
  const int tid  = threadIdx.x;
  const int lane = tid & 63;
  const int lw   = tid >> 6;                 // wave 0..7
  const int g    = tid >> 4;                 // 16-lane group 0..31
  const int gl   = tid & 15;
  const int b    = blockIdx.x;

  // ---- LDS (~12 KB) ----
  __shared__ __align__(16) float s_x[1536];          // carry [ha|hm|h]
  __shared__ __align__(16) float s_c[1024];          // [ca|cm]
  __shared__ float s_ar[112], s_awa[112], s_awm[112], s_aw[4];

  // ---- static assignment maps ----
  const int r0a = (b + 51) & 63;                 // gwpa rows r0a, r0a+64(if<36)
  const int r1m = (b + 25) & 63;                 // gwpm rows
  const bool big1_grp = (b < 36);
  const bool big1_wp  = (b >= 40 && b <= 42);

  if (tid < 112) { s_ar[tid] = 0.f; s_awa[tid] = 0.f; s_awm[tid] = 0.f; }
  if (tid < 4) s_aw[tid] = 0.f;

  // ---- per-thread roles ----
  // phase A group jobs: wave1(g4-7)=ca0-3, wave5(g20-23)=ca4-7,
  // waves2-3(g8-15)=cm, wave4(g16-19)=small gates, waves6/7=big gates.
  // wave0: NO phase A — dedicated critical grp-poll + ar softmax.
  int dstA = -1, xoffA = 0, strideA = 512;
  bool reluA = false;
  float biasA = 0.f;
  const float* preAPtr = nullptr;
  const float* wARow = nullptr;
  if (g >= 4 && g < 8) {
    int col = b * 8 + (g - 4);
    dstA = col; reluA = true; biasA = a.b_ca[col]; preAPtr = a.PAca + col;
    wARow = a.TWca + (size_t)col * 512; xoffA = 0;
  } else if (g >= 20 && g < 24) {
    int col = b * 8 + (g - 16);
    dstA = col; reluA = true; biasA = a.b_ca[col]; preAPtr = a.PAca + col;
    wARow = a.TWca + (size_t)col * 512; xoffA = 0;
  } else if (g >= 8 && g < 16) {
    int col = b * 8 + (g - 8);
    dstA = 512 + col; reluA = true; biasA = a.b_cm[col]; preAPtr = a.PMcm + col;
    wARow = a.TWcm + (size_t)col * 512; xoffA = 512;
  } else if (g >= 16 && g < 20) {
    int sl = g - 16;
    strideA = 100;
    if (sl == 0)                  { dstA = 1124 + r0a;      biasA = a.b_wpa[r0a];      preAPtr = a.PAwpa + r0a;      wARow = a.TWwpa + (size_t)r0a * 512;        xoffA = 0;   }
    else if (sl == 1 && r0a < 36) { dstA = 1124 + r0a + 64; biasA = a.b_wpa[r0a + 64]; preAPtr = a.PAwpa + r0a + 64; wARow = a.TWwpa + (size_t)(r0a + 64) * 512; xoffA = 0;   }
    else if (sl == 2)             { dstA = 1224 + r1m;      biasA = a.b_wpm[r1m];      preAPtr = a.PMwpm + r1m;      wARow = a.TWwpm + (size_t)r1m * 512;        xoffA = 512; }
    else if (sl == 3 && r1m < 36) { dstA = 1224 + r1m + 64; biasA = a.b_wpm[r1m + 64]; preAPtr = a.PMwpm + r1m + 64; wARow = a.TWwpm + (size_t)(r1m + 64) * 512; xoffA = 512; }
  }
  int dstBig = -1;
  float biasBig = 0.f;
  const float* wBigRow = nullptr;
  if (lw == 6) { dstBig = 1024 + b; biasBig = a.b_rp[b]; wBigRow = a.TWrp + (size_t)b * 1536; }
  else if (lw == 7) {
    if (big1_grp)      { dstBig = 1024 + b + 64;   biasBig = a.b_rp[b + 64]; wBigRow = a.TWrp + (size_t)(b + 64) * 1536; }
    else if (big1_wp)  { dstBig = 1324 + (b - 40); biasBig = a.b_wp[b - 40]; wBigRow = a.TWwp + (size_t)(b - 40) * 1536; }
  }
  // owners: groups 8..31 own q = b*24 + (g-8)  (waves 2-7)
  const bool own = (g >= 8);
  const int rr = g - 8;
  int ownHsel = 0, ownJ = 0, whXo = 0, qOwn = 0;
  float biasO = 0.f;
  const float* preOPtr = nullptr;
  const float* whRow = nullptr;
  const float* uRow = nullptr;
  if (own) {
    qOwn = b * OWNB + rr;
    int hsel = qOwn >> 9, j = qOwn & 511;
    ownHsel = hsel; ownJ = j;
    if (hsel == 0)      { biasO = a.b_rh[j];
                          whRow = a.TWh0 + (size_t)j * 512; whXo = 1024;
                          uRow  = a.TWu0 + (size_t)j * 512; }
    else if (hsel == 1) { biasO = a.b_rha[j]; preOPtr = a.PArha + j;
                          whRow = a.TWh1 + (size_t)j * 512; whXo = 0;
                          uRow  = a.TWu1 + (size_t)j * 512; }
    else                { biasO = a.b_rhm[j]; preOPtr = a.PMrhm + j;
                          whRow = a.TWh2 + (size_t)j * 512; whXo = 512;
                          uRow  = a.TWu2 + (size_t)j * 512; }
  }

  // ---- register-pinned weights (time-invariant; loaded once) ----
  float4 wA[8];   // phase-A row slice
  float4 wU[8];   // owned u-row slice
  float4 wWh[8];  // owned wh-row slice
  float4 wB[6];   // big-gate row slice (waves 6/7)
  float  gr[7];   // G memory rows (private to owning group)
  #pragma unroll
  for (int it = 0; it < 8; ++it) wA[it] = wU[it] = wWh[it] = make_float4(0.f, 0.f, 0.f, 0.f);
  #pragma unroll
  for (int it = 0; it < 6; ++it) wB[it] = make_float4(0.f, 0.f, 0.f, 0.f);
  #pragma unroll
  for (int k = 0; k < 7; ++k) gr[k] = 0.f;

  if (wARow) {
    const float4* w4 = (const float4*)wARow;
    #pragma unroll
    for (int it = 0; it < 8; ++it) wA[it] = w4[gl + 16 * it];
  }
  if (own) {
    const float4* u4 = (const float4*)uRow;
    const float4* h4 = (const float4*)whRow;
    #pragma unroll
    for (int it = 0; it < 8; ++it) { wU[it] = u4[gl + 16 * it]; wWh[it] = h4[gl + 16 * it]; }
  }
  if (wBigRow) {
    const float4* w4 = (const float4*)wBigRow;
    #pragma unroll
    for (int it = 0; it < 6; ++it) wB[it] = w4[lane + 64 * it];
  }
  __syncthreads();

  // ---- prologue: software-pipelined per-step scalars (value for t=0) ----
  float preA_c = preAPtr ? preAPtr[0] : 0.f;
  float preO_c = preOPtr ? preOPtr[0] : 0.f;

  // ---------------- time loop (SYNC0 / SYNC1 / SYNC2) ----------------
  for (int t = 0; t < a.nT; ++t) {
    const unsigned tagB = (unsigned)t + 1;
    unsigned long long* bc = a.bcast + (size_t)(t & 1) * 1344;

    // ---- poll carry(t): 3 slots/thread ----
    {
      const unsigned long long* cin = a.carryT + (size_t)(t & 1) * 1536;
      int i0 = tid, i1 = tid + 512, i2 = tid + 1024;
      unsigned long long v0 = ald(cin + i0), v1 = ald(cin + i1), v2 = ald(cin + i2);
      while (((unsigned)(v0 >> 32) < tagB) | ((unsigned)(v1 >> 32) < tagB) |
             ((unsigned)(v2 >> 32) < tagB)) {
        __builtin_amdgcn_s_sleep(1);
        v0 = ald(cin + i0); v1 = ald(cin + i1); v2 = ald(cin + i2);
      }
      s_x[i0] = __uint_as_float((unsigned)v0);
      s_x[i1] = __uint_as_float((unsigned)v1);
      s_x[i2] = __uint_as_float((unsigned)v2);
    }
    __syncthreads();   // SYNC0

    // issue NEXT step's prefetches now (whole step to land)
    const int tn = (t + 1 < a.nT) ? t + 1 : t;
    float preA_n = preAPtr ? preAPtr[(size_t)tn * strideA] : 0.f;
    float preO_n = preOPtr ? preOPtr[(size_t)tn * 512] : 0.f;

    // ---- phase A: all bcast publishes in one parallel round ----
    if (dstA >= 0) {
      const float4* x4 = (const float4*)(s_x + xoffA);
      float acc = 0.f;
      #pragma unroll
      for (int it = 0; it < 8; ++it) {
        float4 xv = x4[gl + 16 * it];
        acc += wA[it].x * xv.x + wA[it].y * xv.y + wA[it].z * xv.z + wA[it].w * xv.w;
      }
      float v = rsum16(acc);
      if (!gl) {
        v += preA_c + biasA;
        if (reluA) v = fmaxf(v, 0.f);
        gstTag(bc + dstA, v, tagB);
      }
    } else if (dstBig >= 0) {
      const float4* x4 = (const float4*)s_x;
      float acc = 0.f;
      #pragma unroll
      for (int it = 0; it < 6; ++it) {
        float4 xv = x4[lane + 64 * it];
        acc += wB[it].x * xv.x + wB[it].y * xv.y + wB[it].z * xv.z + wB[it].w * xv.w;
      }
      float v = xrsum(acc);
      if (!lane) gstTag(bc + dstBig, v + biasBig, tagB);
    }
    // wh dot (register weights; feeds h')
    float whv = 0.f;
    if (own) {
      const float4* x4 = (const float4*)(s_x + whXo);
      float acc = 0.f;
      #pragma unroll
      for (int it = 0; it < 8; ++it) {
        float4 xv = x4[gl + 16 * it];
        acc += wWh[it].x * xv.x + wWh[it].y * xv.y + wWh[it].z * xv.z + wWh[it].w * xv.w;
      }
      whv = rsum16(acc);
    }

    // ---- CRITICAL: wave 0 polls grp logits + ar softmax ----
    if (lw == 0) {
      const unsigned long long* p1 = bc + 1024 + lane;
      bool two = lane < 36;
      unsigned long long v1 = ald(p1);
      unsigned long long v2 = two ? ald(p1 + 64) : ~0ull;
      while (((unsigned)(v1 >> 32) < tagB) | ((unsigned)(v2 >> 32) < tagB)) {
        __builtin_amdgcn_s_sleep(1);
        v1 = ald(p1); if (two) v2 = ald(p1 + 64);
      }
      float x1 = __uint_as_float((unsigned)v1);
      float x2 = two ? __uint_as_float((unsigned)v2) : -3.0e38f;
      float m = fmaxf(x1, x2);
      #pragma unroll
      for (int o = 32; o; o >>= 1) m = fmaxf(m, __shfl_xor(m, o, 64));
      float e1 = expf(x1 - m);
      float e2 = two ? expf(x2 - m) : 0.f;
      float ss = e1 + e2;
      #pragma unroll
      for (int o = 32; o; o >>= 1) ss += __shfl_xor(ss, o, 64);
      float inv = 1.f / ss;
      s_ar[lane] = e1 * inv;
      if (two) s_ar[64 + lane] = e2 * inv;
    }
    __syncthreads();   // SYNC1: gated only by wave0's grp chain

    // ---- CRITICAL: owners publish h' immediately ----
    unsigned long long* cout = a.carryT + (size_t)((t + 1) & 1) * 1536;
    if (own) {
      float contrib = 0.f;
      #pragma unroll
      for (int k = 0; k < 7; ++k) contrib += s_ar[gl + 16 * k] * gr[k];
      contrib = rsum16(contrib);
      if (!gl) {
        float h = fmaxf(contrib + whv + preO_c + biasO, 0.f);
        if (ownHsel == 0) {
          a.out[(size_t)t * 512 + ownJ] = h;
          gstTag(cout + 1024 + ownJ, h, tagB + 1);
        } else if (ownHsel == 1) {
          gstTag(cout + ownJ, h, tagB + 1);
        } else {
          gstTag(cout + 512 + ownJ, h, tagB + 1);
        }
      }
    }

    // ---- off-critical side polls (data already landed -> quick exit) ----
    if (lw == 0) {         // awa/awm/wp softmaxes
      bool two = lane < 36, wpx = lane < 3;
      const unsigned long long* pa = bc + 1124 + lane;
      const unsigned long long* pm = bc + 1224 + lane;
      const unsigned long long* pw = bc + 1324 + lane;
      unsigned long long a1 = ald(pa), m1 = ald(pm);
      unsigned long long a2 = two ? ald(pa + 64) : ~0ull;
      unsigned long long m2 = two ? ald(pm + 64) : ~0ull;
      unsigned long long w1 = wpx ? ald(pw) : ~0ull;
      while (((unsigned)(a1 >> 32) < tagB) | ((unsigned)(a2 >> 32) < tagB) |
             ((unsigned)(m1 >> 32) < tagB) | ((unsigned)(m2 >> 32) < tagB) |
             ((unsigned)(w1 >> 32) < tagB)) {
        __builtin_amdgcn_s_sleep(1);
        a1 = ald(pa); m1 = ald(pm);
        if (two) { a2 = ald(pa + 64); m2 = ald(pm + 64); }
        if (wpx) w1 = ald(pw);
      }
      {
        float x1 = __uint_as_float((unsigned)a1);
        float x2 = two ? __uint_as_float((unsigned)a2) : -3.0e38f;
        float m = fmaxf(x1, x2);
        #pragma unroll
        for (int o = 32; o; o >>= 1) m = fmaxf(m, __shfl_xor(m, o, 64));
        float e1 = expf(x1 - m);
        float e2 = two ? expf(x2 - m) : 0.f;
        float ss = e1 + e2;
        #pragma unroll
        for (int o = 32; o; o >>= 1) ss += __shfl_xor(ss, o, 64);
        float inv = 1.f / ss;
        s_awa[lane] = e1 * inv;
        if (two) s_awa[64 + lane] = e2 * inv;
      }
      {
        float x1 = __uint_as_float((unsigned)m1);
        float x2 = two ? __uint_as_float((unsigned)m2) : -3.0e38f;
        float m = fmaxf(x1, x2);
        #pragma unroll
        for (int o = 32; o; o >>= 1) m = fmaxf(m, __shfl_xor(m, o, 64));
        float e1 = expf(x1 - m);
        float e2 = two ? expf(x2 - m) : 0.f;
        float ss = e1 + e2;
        #pragma unroll
        for (int o = 32; o; o >>= 1) ss += __shfl_xor(ss, o, 64);
        float inv = 1.f / ss;
        s_awm[lane] = e1 * inv;
        if (two) s_awm[64 + lane] = e2 * inv;
      }
      {
        float x = wpx ? __uint_as_float((unsigned)w1) : -3.0e38f;
        float m = x;
        #pragma unroll
        for (int o = 32; o; o >>= 1) m = fmaxf(m, __shfl_xor(m, o, 64));
        float e = wpx ? expf(x - m) : 0.f;
        float ss = e;
        #pragma unroll
        for (int o = 32; o; o >>= 1) ss += __shfl_xor(ss, o, 64);
        if (wpx) s_aw[lane] = e / ss;
      }
    } else if (lw == 1) {  // c-gather: 16 slots/lane
      const unsigned long long* p = bc + lane;
      unsigned long long v[16];
      #pragma unroll
      for (int k = 0; k < 16; ++k) v[k] = ald(p + 64 * k);
      for (;;) {
        bool ok = true;
        #pragma unroll
        for (int k = 0; k < 16; ++k) ok &= ((unsigned)(v[k] >> 32) >= tagB);
        if (__all(ok)) break;
        __builtin_amdgcn_s_sleep(1);
        #pragma unroll
        for (int k = 0; k < 16; ++k) v[k] = ald(p + 64 * k);
      }
      #pragma unroll
      for (int k = 0; k < 16; ++k) s_c[lane + 64 * k] = __uint_as_float((unsigned)v[k]);
    }
    __syncthreads();   // SYNC2: s_c / s_aw* ready

    // ---- owners' tail: u-dot + G update (shadowed by next x-observe) ----
    if (own) {
      const float4* a4 = (const float4*)s_c;
      const float4* m4 = (const float4*)(s_c + 512);
      float sa = 0.f, sm = 0.f;
      #pragma unroll
      for (int it = 0; it < 8; ++it) {
        float4 av = a4[gl + 16 * it], mv = m4[gl + 16 * it];
        sa += wU[it].x * av.x + wU[it].y * av.y + wU[it].z * av.z + wU[it].w * av.w;
        sm += wU[it].x * mv.x + wU[it].y * mv.y + wU[it].z * mv.z + wU[it].w * mv.w;
      }
      #pragma unroll
      for (int o = 8; o; o >>= 1) { sa += __shfl_xor(sa, o, 64); sm += __shfl_xor(sm, o, 64); }
      const float uA = sa, uM = sm;
      const float aw0 = s_aw[0], aw1 = s_aw[1], aw2 = s_aw[2];
      #pragma unroll
      for (int k = 0; k < 7; ++k) {
        int idx = gl + 16 * k;
        gr[k] = aw0 * gr[k] + aw1 * s_awa[idx] * uA + aw2 * s_awm[idx] * uM;
      }
    }
    // hazard fences: s_x(t+1) writes happen only after the writer passed
    // SYNC2(t) (all step-t s_x reads done). s_c/s_aw*(t+1) writes happen
    // after SYNC0(t+1), which needs owners (who just read them) to arrive.

    preA_c = preA_n;
    preO_c = preO_n;
  }
}

// ---------------- host ----------------
extern "C" void kernel_launch(void* const* d_in, const int* in_sizes, int n_in,
                              void* d_out, int out_size, void* d_ws, size_t ws_size,
                              hipStream_t stream) {
  const float* Xa    = (const float*)d_in[0];
  const float* Xm    = (const float*)d_in[1];
  const float* W_ca  = (const float*)d_in[2];  const float* b_ca  = (const float*)d_in[3];
  const float* W_cm  = (const float*)d_in[4];  const float* b_cm  = (const float*)d_in[5];
  const float* W_wp  = (const float*)d_in[6];  const float* b_wp  = (const float*)d_in[7];
  const float* W_wpa = (const float*)d_in[8];  const float* b_wpa = (const float*)d_in[9];
  const float* W_wpm = (const float*)d_in[10]; const float* b_wpm = (const float*)d_in[11];
  const float* W_rp  = (const float*)d_in[12]; const float* b_rp  = (const float*)d_in[13];
  const float* W_rh  = (const float*)d_in[14]; const float* b_rh  = (const float*)d_in[15];
  const float* W_rha = (const float*)d_in[16]; const float* b_rha = (const float*)d_in[17];
  const float* W_rhm = (const float*)d_in[18]; const float* b_rhm = (const float*)d_in[19];

  int nT = out_size / HS;   // 4096
  float* ws = (float*)d_ws;

  initK<<<dim3(64), dim3(256), 0, stream>>>(
      (unsigned long long*)(ws + OFF_CARRY),
      (unsigned long long*)(ws + OFF_BCAST));

  dim3 tb(32, 8);
  auto tg = [](int R, int C) { return dim3((C + 31) / 32, (R + 31) / 32); };
  transK<<<tg(1536, 100), tb, 0, stream>>>(W_rp,                       ws + OFF_TWrp,  1536, 100);
  transK<<<tg(1536, 3),   tb, 0, stream>>>(W_wp,                       ws + OFF_TWwp,  1536, 3);
  transK<<<tg(512, 100),  tb, 0, stream>>>(W_wpa,                      ws + OFF_TWwpa, 512, 100);
  transK<<<tg(512, 100),  tb, 0, stream>>>(W_wpm,                      ws + OFF_TWwpm, 512, 100);
  transK<<<tg(512, 512),  tb, 0, stream>>>(W_ca,                       ws + OFF_TWca,  512, 512);
  transK<<<tg(512, 512),  tb, 0, stream>>>(W_cm,                       ws + OFF_TWcm,  512, 512);
  transK<<<tg(512, 512),  tb, 0, stream>>>(W_rh  + 512 * 512,          ws + OFF_TWh0,  512, 512);
  transK<<<tg(512, 512),  tb, 0, stream>>>(W_rha + (size_t)2560 * 512, ws + OFF_TWh1,  512, 512);
  transK<<<tg(512, 512),  tb, 0, stream>>>(W_rhm + (size_t)2560 * 512, ws + OFF_TWh2,  512, 512);
  transK<<<tg(512, 512),  tb, 0, stream>>>(W_rh,                       ws + OFF_TWu0,  512, 512);
  transK<<<tg(512, 512),  tb, 0, stream>>>(W_rha + (size_t)2048 * 512, ws + OFF_TWu1,  512, 512);
  transK<<<tg(512, 512),  tb, 0, stream>>>(W_rhm + (size_t)2048 * 512, ws + OFF_TWu2,  512, 512);

  int tB = nT / 128;
  gemm128<<<dim3(4, tB), dim3(256), 0, stream>>>(Xa, W_ca + (size_t)512 * 512, ws + OFF_PAca);
  gemm128<<<dim3(4, tB), dim3(256), 0, stream>>>(Xm, W_cm + (size_t)512 * 512, ws + OFF_PMcm);
  gemm128<<<dim3(4, tB), dim3(256), 0, stream>>>(Xa, W_rha,                    ws + OFF_PArha);
  gemm128<<<dim3(4, tB), dim3(256), 0, stream>>>(Xm, W_rhm,                    ws + OFF_PMrhm);
  int tB64 = nT / 64;
  gemmK<<<dim3(2, tB64), dim3(256), 0, stream>>>(Xa, W_wpa + (size_t)512 * 100, ws + OFF_PAwpa, 100);
  gemmK<<<dim3(2, tB64), dim3(256), 0, stream>>>(Xm, W_wpm + (size_t)512 * 100, ws + OFF_PMwpm, 100);

  RArgs a;
  a.TWrp  = ws + OFF_TWrp;  a.TWwp  = ws + OFF_TWwp;
  a.TWwpa = ws + OFF_TWwpa; a.TWwpm = ws + OFF_TWwpm;
  a.TWca  = ws + OFF_TWca;  a.TWcm  = ws + OFF_TWcm;
  a.TWh0  = ws + OFF_TWh0;  a.TWh1  = ws + OFF_TWh1;  a.TWh2 = ws + OFF_TWh2;
  a.TWu0  = ws + OFF_TWu0;  a.TWu1  = ws + OFF_TWu1;  a.TWu2 = ws + OFF_TWu2;
  a.PAca  = ws + OFF_PAca;  a.PMcm  = ws + OFF_PMcm;
  a.PArha = ws + OFF_PArha; a.PMrhm = ws + OFF_PMrhm;
  a.PAwpa = ws + OFF_PAwpa; a.PMwpm = ws + OFF_PMwpm;
  a.b_ca = b_ca; a.b_cm = b_cm; a.b_wp = b_wp; a.b_wpa = b_wpa; a.b_wpm = b_wpm;
  a.b_rp = b_rp; a.b_rh = b_rh; a.b_rha = b_rha; a.b_rhm = b_rhm;
  a.carryT = (unsigned long long*)(ws + OFF_CARRY);
  a.bcast  = (unsigned long long*)(ws + OFF_BCAST);
  a.out    = (float*)d_out;
  a.nT     = nT;

  recurK<<<dim3(GBLK), dim3(TPB), 0, stream>>>(a);
}

// Round 11
// 22723.421 us; speedup vs baseline: 4.2823x; 1.2089x over previous
//
#include <hip/hip_runtime.h>
#include <cstdint>
#include <cstddef>

#define HS 512

constexpr int TPB  = 512;            // 8 waves/block
constexpr int GBLK = 64;
constexpr int OWNB = 24;             // owned carry rows per block (one per 16-lane group)

// ---------------- workspace layout (float offsets) ----------------
constexpr size_t OFF_TWrp  = 0;                       // [100][1536]
constexpr size_t OFF_TWwp  = OFF_TWrp  + 100*1536;    // [3][1536]
constexpr size_t OFF_TWwpa = OFF_TWwp  + 3*1536;      // [100][512]
constexpr size_t OFF_TWwpm = OFF_TWwpa + 100*512;
constexpr size_t OFF_TWca  = OFF_TWwpm + 100*512;     // [512][512]
constexpr size_t OFF_TWcm  = OFF_TWca  + 512*512;
constexpr size_t OFF_TWh0  = OFF_TWcm  + 512*512;     // W_rh[512:1024)^T   (h)
constexpr size_t OFF_TWh1  = OFF_TWh0  + 512*512;     // W_rha[2560:3072)^T (ha)
constexpr size_t OFF_TWh2  = OFF_TWh1  + 512*512;     // W_rhm[2560:3072)^T (hm)
constexpr size_t OFF_TWu0  = OFF_TWh2  + 512*512;     // W_rh[0:512)^T      (r)
constexpr size_t OFF_TWu1  = OFF_TWu0  + 512*512;     // W_rha[2048:2560)^T
constexpr size_t OFF_TWu2  = OFF_TWu1  + 512*512;     // W_rhm[2048:2560)^T
constexpr size_t OFF_PAca  = OFF_TWu2  + 512*512;     // [4096][512]
constexpr size_t OFF_PMcm  = OFF_PAca  + 4096*512;
constexpr size_t OFF_PArha = OFF_PMcm  + 4096*512;
constexpr size_t OFF_PMrhm = OFF_PArha + 4096*512;
constexpr size_t OFF_PAwpa = OFF_PMrhm + 4096*512;    // [4096][100]
constexpr size_t OFF_PMwpm = OFF_PAwpa + 4096*100;
constexpr size_t OFF_CARRY = OFF_PMwpm + 4096*100;    // u64[2][1536] tagged
constexpr size_t OFF_BCAST = OFF_CARRY + 2*1536*2;    // u64[2][1344] tagged
// bcast: [0:512) ca  [512:1024) cm  [1024:1124) grp  [1124:1224) gwpa
//        [1224:1324) gwpm  [1324:1327) wp

// ---------------- device helpers ----------------
__device__ __forceinline__ unsigned long long ald(const unsigned long long* p) {
  return __hip_atomic_load(const_cast<unsigned long long*>(p),
                           __ATOMIC_RELAXED, __HIP_MEMORY_SCOPE_AGENT);
}
__device__ __forceinline__ void gstTag(unsigned long long* p, float v, unsigned tag) {
  unsigned long long u = ((unsigned long long)tag << 32) | (unsigned long long)__float_as_uint(v);
  __hip_atomic_store(p, u, __ATOMIC_RELAXED, __HIP_MEMORY_SCOPE_AGENT);
}
__device__ __forceinline__ float xrsum(float v) {
  #pragma unroll
  for (int o = 32; o; o >>= 1) v += __shfl_xor(v, o, 64);
  return v;
}
__device__ __forceinline__ float rsum16(float v) {
  // xor masks < 16 keep exchange within the 16-lane group
  #pragma unroll
  for (int o = 8; o; o >>= 1) v += __shfl_xor(v, o, 64);
  return v;
}

// ---------------- prep kernels ----------------
__global__ void initK(unsigned long long* carryT, unsigned long long* bcast) {
  int i = blockIdx.x * blockDim.x + threadIdx.x, st = gridDim.x * blockDim.x;
  for (int k = i; k < 1536; k += st) carryT[k] = (1ull << 32);   // carry(0)=0, tag 1
  for (int k = i; k < 1536; k += st) carryT[1536 + k] = 0ull;
  for (int k = i; k < 2 * 1344; k += st) bcast[k] = 0ull;
}

__global__ void transK(const float* __restrict__ src, float* __restrict__ dst, int R, int C) {
  __shared__ float tile[32][33];
  int c0 = blockIdx.x * 32, r0 = blockIdx.y * 32;
  for (int i = threadIdx.y; i < 32; i += 8) {
    int r = r0 + i, c = c0 + threadIdx.x;
    tile[i][threadIdx.x] = (r < R && c < C) ? src[(size_t)r * C + c] : 0.f;
  }
  __syncthreads();
  for (int i = threadIdx.y; i < 32; i += 8) {
    int c = c0 + i, r = r0 + threadIdx.x;
    if (c < C && r < R) dst[(size_t)c * R + r] = tile[threadIdx.x][i];
  }
}

__global__ __launch_bounds__(256) void gemmK(const float* __restrict__ X,
                                             const float* __restrict__ W,
                                             float* __restrict__ C, int N) {
  __shared__ float As[16][68];
  __shared__ float Bs[16][68];
  int t0 = blockIdx.y * 64, n0 = blockIdx.x * 64;
  int tid = threadIdx.x, tx = tid & 15, ty = tid >> 4;
  float acc[4][4] = {};
  for (int k0 = 0; k0 < 2048; k0 += 16) {
    {
      int r = tid >> 2, c = (tid & 3) * 4;
      float4 v = *(const float4*)(X + (size_t)(t0 + r) * 2048 + k0 + c);
      As[c + 0][r] = v.x; As[c + 1][r] = v.y; As[c + 2][r] = v.z; As[c + 3][r] = v.w;
    }
    {
      int kr = tid >> 4, c = (tid & 15) * 4;
      int gcol = n0 + c;
      const float* src = W + (size_t)(k0 + kr) * N + gcol;
      #pragma unroll
      for (int i = 0; i < 4; ++i) Bs[kr][c + i] = (gcol + i < N) ? src[i] : 0.f;
    }
    __syncthreads();
    #pragma unroll
    for (int kk = 0; kk < 16; ++kk) {
      float4 a4 = *(const float4*)&As[kk][ty * 4];
      float4 b4 = *(const float4*)&Bs[kk][tx * 4];
      float av[4] = {a4.x, a4.y, a4.z, a4.w};
      float bv[4] = {b4.x, b4.y, b4.z, b4.w};
      #pragma unroll
      for (int i = 0; i < 4; ++i)
        #pragma unroll
        for (int j = 0; j < 4; ++j) acc[i][j] += av[i] * bv[j];
    }
    __syncthreads();
  }
  #pragma unroll
  for (int i = 0; i < 4; ++i)
    #pragma unroll
    for (int j = 0; j < 4; ++j) {
      int col = n0 + tx * 4 + j;
      if (col < N) C[(size_t)(t0 + ty * 4 + i) * N + col] = acc[i][j];
    }
}

__global__ __launch_bounds__(256) void gemm128(const float* __restrict__ X,
                                               const float* __restrict__ W,
                                               float* __restrict__ C) {
  __shared__ float As[8][132];
  __shared__ float Bs[8][132];
  const int N = 512;
  int t0 = blockIdx.y * 128, n0 = blockIdx.x * 128;
  int tid = threadIdx.x, tx = tid & 15, ty = tid >> 4;
  float acc[8][8] = {};
  for (int k0 = 0; k0 < 2048; k0 += 8) {
    int r = tid >> 1, c4 = (tid & 1) * 4;
    float4 va = *(const float4*)(X + (size_t)(t0 + r) * 2048 + k0 + c4);
    int kr = tid >> 5, cb = (tid & 31) * 4;
    float4 vb = *(const float4*)(W + (size_t)(k0 + kr) * N + n0 + cb);
    __syncthreads();
    As[c4 + 0][r] = va.x; As[c4 + 1][r] = va.y; As[c4 + 2][r] = va.z; As[c4 + 3][r] = va.w;
    Bs[kr][cb] = vb.x; Bs[kr][cb + 1] = vb.y; Bs[kr][cb + 2] = vb.z; Bs[kr][cb + 3] = vb.w;
    __syncthreads();
    #pragma unroll
    for (int kk = 0; kk < 8; ++kk) {
      float av[8], bv[8];
      *(float4*)av       = *(const float4*)&As[kk][ty * 8];
      *(float4*)(av + 4) = *(const float4*)&As[kk][ty * 8 + 4];
      *(float4*)bv       = *(const float4*)&Bs[kk][tx * 8];
      *(float4*)(bv + 4) = *(const float4*)&Bs[kk][tx * 8 + 4];
      #pragma unroll
      for (int i = 0; i < 8; ++i)
        #pragma unroll
        for (int j = 0; j < 8; ++j) acc[i][j] += av[i] * bv[j];
    }
  }
  #pragma unroll
  for (int i = 0; i < 8; ++i) {
    float* dst = C + (size_t)(t0 + ty * 8 + i) * N + n0 + tx * 8;
    *(float4*)dst       = *(float4*)&acc[i][0];
    *(float4*)(dst + 4) = *(float4*)&acc[i][4];
  }
}

// ---------------- persistent recurrence kernel ----------------
struct RArgs {
  const float *TWrp, *TWwp, *TWwpa, *TWwpm, *TWca, *TWcm;
  const float *TWh0, *TWh1, *TWh2, *TWu0, *TWu1, *TWu2;
  const float *PAca, *PMcm, *PArha, *PMrhm, *PAwpa, *PMwpm;
  const float *b_ca, *b_cm, *b_wp, *b_wpa, *b_wpm, *b_rp, *b_rh, *b_rha, *b_rhm;
  unsigned long long *carryT, *bcast;
  float *out;
  int nT;
};

__global__ __launch_bounds__(TPB, 1) void recurK(RArgs a) {
  const int tid  = threadIdx.x;
  const int lane = tid & 63;
  const int lw   = tid >> 6;                 // wave 0..7
  const int g    = tid >> 4;                 // 16-lane group 0..31
  const int gl   = tid & 15;
  const int b    = blockIdx.x;

  // ---- LDS (~12 KB: all weights + G live in registers) ----
  __shared__ __align__(16) float s_x[1536];          // carry [ha|hm|h]
  __shared__ __align__(16) float s_c[1024];          // [ca|cm]
  __shared__ float s_ar[112], s_awa[112], s_awm[112], s_aw[4];

  // ---- static assignment maps ----
  const int r0a = (b + 51) & 63;                 // gwpa rows r0a, r0a+64(if<36)
  const int r1m = (b + 25) & 63;                 // gwpm rows
  const bool big1_grp = (b < 36);
  const bool big1_wp  = (b >= 40 && b <= 42);

  if (tid < 112) { s_ar[tid] = 0.f; s_awa[tid] = 0.f; s_awm[tid] = 0.f; }

  // ---- per-thread roles ----
  // phase A group jobs: waves 0-1 = ca cols, 2-3 = cm cols, 4 = small gates,
  // 5 = none (does wh only), 6 = big0 (grp b), 7 = big1 (grp b+64 / wp)
  int dstA = -1, xoffA = 0, strideA = 512;
  bool reluA = false;
  float biasA = 0.f;
  const float* preAPtr = nullptr;
  const float* wARow = nullptr;
  if (lw < 2) {
    int col = b * 8 + g;
    dstA = col; reluA = true; biasA = a.b_ca[col]; preAPtr = a.PAca + col;
    wARow = a.TWca + (size_t)col * 512; xoffA = 0;
  } else if (lw < 4) {
    int col = b * 8 + (g - 8);
    dstA = 512 + col; reluA = true; biasA = a.b_cm[col]; preAPtr = a.PMcm + col;
    wARow = a.TWcm + (size_t)col * 512; xoffA = 512;
  } else if (lw == 4) {
    int sl = g - 16;
    strideA = 100;
    if (sl == 0)                  { dstA = 1124 + r0a;      biasA = a.b_wpa[r0a];      preAPtr = a.PAwpa + r0a;      wARow = a.TWwpa + (size_t)r0a * 512;        xoffA = 0;   }
    else if (sl == 1 && r0a < 36) { dstA = 1124 + r0a + 64; biasA = a.b_wpa[r0a + 64]; preAPtr = a.PAwpa + r0a + 64; wARow = a.TWwpa + (size_t)(r0a + 64) * 512; xoffA = 0;   }
    else if (sl == 2)             { dstA = 1224 + r1m;      biasA = a.b_wpm[r1m];      preAPtr = a.PMwpm + r1m;      wARow = a.TWwpm + (size_t)r1m * 512;        xoffA = 512; }
    else if (sl == 3 && r1m < 36) { dstA = 1224 + r1m + 64; biasA = a.b_wpm[r1m + 64]; preAPtr = a.PMwpm + r1m + 64; wARow = a.TWwpm + (size_t)(r1m + 64) * 512; xoffA = 512; }
  }
  int dstBig = -1;
  float biasBig = 0.f;
  const float* wBigRow = nullptr;
  if (lw == 6) { dstBig = 1024 + b; biasBig = a.b_rp[b]; wBigRow = a.TWrp + (size_t)b * 1536; }
  else if (lw == 7) {
    if (big1_grp)      { dstBig = 1024 + b + 64;   biasBig = a.b_rp[b + 64]; wBigRow = a.TWrp + (size_t)(b + 64) * 1536; }
    else if (big1_wp)  { dstBig = 1324 + (b - 40); biasBig = a.b_wp[b - 40]; wBigRow = a.TWwp + (size_t)(b - 40) * 1536; }
  }
  // owned / wh: group g < 24 owns carry row q = b*24+g (wh row == owned row)
  const bool own = (g < OWNB);
  int ownHsel = 0, ownJ = 0, whXo = 0;
  float biasO = 0.f;
  const float* preOPtr = nullptr;
  const float* whRow = nullptr;
  const float* uRow = nullptr;
  if (own) {
    int q = b * OWNB + g, hsel = q >> 9, j = q & 511;
    ownHsel = hsel; ownJ = j;
    if (hsel == 0)      { biasO = a.b_rh[j];
                          whRow = a.TWh0 + (size_t)j * 512; whXo = 1024;
                          uRow  = a.TWu0 + (size_t)j * 512; }
    else if (hsel == 1) { biasO = a.b_rha[j]; preOPtr = a.PArha + j;
                          whRow = a.TWh1 + (size_t)j * 512; whXo = 0;
                          uRow  = a.TWu1 + (size_t)j * 512; }
    else                { biasO = a.b_rhm[j]; preOPtr = a.PMrhm + j;
                          whRow = a.TWh2 + (size_t)j * 512; whXo = 512;
                          uRow  = a.TWu2 + (size_t)j * 512; }
  }

  // ---- register-pinned weights (time-invariant; loaded once) ----
  float4 wA[8];   // phase-A row slice (waves 0-4 with a job)
  float4 wU[8];   // owned u-row slice
  float4 wWh[8];  // owned wh-row slice
  float4 wB[6];   // big-gate row slice (waves 6/7)
  float  gr[7];   // G memory rows: private to the owning group
  #pragma unroll
  for (int it = 0; it < 8; ++it) wA[it] = wU[it] = wWh[it] = make_float4(0.f, 0.f, 0.f, 0.f);
  #pragma unroll
  for (int it = 0; it < 6; ++it) wB[it] = make_float4(0.f, 0.f, 0.f, 0.f);
  #pragma unroll
  for (int k = 0; k < 7; ++k) gr[k] = 0.f;

  if (wARow) {
    const float4* w4 = (const float4*)wARow;
    #pragma unroll
    for (int it = 0; it < 8; ++it) wA[it] = w4[gl + 16 * it];
  }
  if (own) {
    const float4* u4 = (const float4*)uRow;
    const float4* h4 = (const float4*)whRow;
    #pragma unroll
    for (int it = 0; it < 8; ++it) { wU[it] = u4[gl + 16 * it]; wWh[it] = h4[gl + 16 * it]; }
  }
  if (wBigRow) {
    const float4* w4 = (const float4*)wBigRow;
    #pragma unroll
    for (int it = 0; it < 6; ++it) wB[it] = w4[lane + 64 * it];
  }
  __syncthreads();

  // ---- prologue: software-pipelined per-step scalars (value for t=0) ----
  float preA_c = preAPtr ? preAPtr[0] : 0.f;
  float preO_c = preOPtr ? preOPtr[0] : 0.f;

  // ---------------- time loop ----------------
  float whv = 0.f;
  for (int t = 0; t < a.nT; ++t) {
    const unsigned tagB = (unsigned)t + 1;
    unsigned long long* bc = a.bcast + (size_t)(t & 1) * 1344;

    // ---- poll carry(t): 3 slots/thread ----
    {
      const unsigned long long* cin = a.carryT + (size_t)(t & 1) * 1536;
      int i0 = tid, i1 = tid + 512, i2 = tid + 1024;
      unsigned long long v0 = ald(cin + i0), v1 = ald(cin + i1), v2 = ald(cin + i2);
      while (((unsigned)(v0 >> 32) < tagB) | ((unsigned)(v1 >> 32) < tagB) |
             ((unsigned)(v2 >> 32) < tagB)) {
        __builtin_amdgcn_s_sleep(1);
        v0 = ald(cin + i0); v1 = ald(cin + i1); v2 = ald(cin + i2);
      }
      s_x[i0] = __uint_as_float((unsigned)v0);
      s_x[i1] = __uint_as_float((unsigned)v1);
      s_x[i2] = __uint_as_float((unsigned)v2);
    }
    __syncthreads();   // SYNC0

    // issue NEXT step's prefetches now: they get the whole step to land
    const int tn = (t + 1 < a.nT) ? t + 1 : t;
    float preA_n = preAPtr ? preAPtr[(size_t)tn * strideA] : 0.f;
    float preO_n = preOPtr ? preOPtr[(size_t)tn * 512] : 0.f;

    // ---- phase A: all critical publishes in ONE parallel round ----
    if (dstA >= 0) {
      const float4* x4 = (const float4*)(s_x + xoffA);
      float acc = 0.f;
      #pragma unroll
      for (int it = 0; it < 8; ++it) {
        float4 xv = x4[gl + 16 * it];
        acc += wA[it].x * xv.x + wA[it].y * xv.y + wA[it].z * xv.z + wA[it].w * xv.w;
      }
      float v = rsum16(acc);
      if (!gl) {
        v += preA_c + biasA;
        if (reluA) v = fmaxf(v, 0.f);
        gstTag(bc + dstA, v, tagB);
      }
    } else if (dstBig >= 0) {
      const float4* x4 = (const float4*)s_x;
      float acc = 0.f;
      #pragma unroll
      for (int it = 0; it < 6; ++it) {
        float4 xv = x4[lane + 64 * it];
        acc += wB[it].x * xv.x + wB[it].y * xv.y + wB[it].z * xv.z + wB[it].w * xv.w;
      }
      float v = xrsum(acc);
      if (!lane) gstTag(bc + dstBig, v + biasBig, tagB);
    }
    // wh dots (register weights; off the inter-block critical path)
    if (own) {
      const float4* x4 = (const float4*)(s_x + whXo);
      float acc = 0.f;
      #pragma unroll
      for (int it = 0; it < 8; ++it) {
        float4 xv = x4[gl + 16 * it];
        acc += wWh[it].x * xv.x + wWh[it].y * xv.y + wWh[it].z * xv.z + wWh[it].w * xv.w;
      }
      whv = rsum16(acc);
    }

    // ---- phase B polls: waves 0-3 softmax groups, waves 4-7 gather c ----
    if (lw < 3) {
      int base = 1024 + lw * 100;       // grp / gwpa / gwpm
      const unsigned long long* p1 = bc + base + lane;
      bool two = lane < 36;
      unsigned long long v1 = ald(p1);
      unsigned long long v2 = two ? ald(p1 + 64) : ~0ull;
      while (((unsigned)(v1 >> 32) < tagB) | ((unsigned)(v2 >> 32) < tagB)) {
        __builtin_amdgcn_s_sleep(1);
        v1 = ald(p1); if (two) v2 = ald(p1 + 64);
      }
      float x1 = __uint_as_float((unsigned)v1);
      float x2 = two ? __uint_as_float((unsigned)v2) : -3.0e38f;
      float m = fmaxf(x1, x2);
      #pragma unroll
      for (int o = 32; o; o >>= 1) m = fmaxf(m, __shfl_xor(m, o, 64));
      float e1 = expf(x1 - m);
      float e2 = two ? expf(x2 - m) : 0.f;
      float ss = e1 + e2;
      #pragma unroll
      for (int o = 32; o; o >>= 1) ss += __shfl_xor(ss, o, 64);
      float inv = 1.f / ss;
      float* dst = (lw == 0) ? s_ar : (lw == 1) ? s_awa : s_awm;
      dst[lane] = e1 * inv;
      if (two) dst[64 + lane] = e2 * inv;
    } else if (lw == 3) {
      float x = -3.0e38f;
      if (lane < 3) {
        const unsigned long long* p = bc + 1324 + lane;
        unsigned long long v = ald(p);
        while ((unsigned)(v >> 32) < tagB) { __builtin_amdgcn_s_sleep(1); v = ald(p); }
        x = __uint_as_float((unsigned)v);
      }
      float m = x;
      #pragma unroll
      for (int o = 32; o; o >>= 1) m = fmaxf(m, __shfl_xor(m, o, 64));
      float e = (lane < 3) ? expf(x - m) : 0.f;
      float ss = e;
      #pragma unroll
      for (int o = 32; o; o >>= 1) ss += __shfl_xor(ss, o, 64);
      if (lane < 3) s_aw[lane] = e / ss;
    } else {
      int base = tid - 256;              // 0..255, 4 slots each
      const unsigned long long* p = bc + base;
      unsigned long long v0 = ald(p), v1 = ald(p + 256), v2 = ald(p + 512), v3 = ald(p + 768);
      while (((unsigned)(v0 >> 32) < tagB) | ((unsigned)(v1 >> 32) < tagB) |
             ((unsigned)(v2 >> 32) < tagB) | ((unsigned)(v3 >> 32) < tagB)) {
        __builtin_amdgcn_s_sleep(1);
        v0 = ald(p); v1 = ald(p + 256); v2 = ald(p + 512); v3 = ald(p + 768);
      }
      s_c[base]       = __uint_as_float((unsigned)v0);
      s_c[base + 256] = __uint_as_float((unsigned)v1);
      s_c[base + 512] = __uint_as_float((unsigned)v2);
      s_c[base + 768] = __uint_as_float((unsigned)v3);
    }
    __syncthreads();   // SYNC1

    // ---- owned phase: ONE parallel round, publish h' BEFORE G update ----
    unsigned long long* cout = a.carryT + (size_t)((t + 1) & 1) * 1536;
    if (own) {
      const float aw0 = s_aw[0], aw1 = s_aw[1], aw2 = s_aw[2];
      // dual u-dot from register weights (uA over ca, uM over cm)
      const float4* a4 = (const float4*)s_c;
      const float4* m4 = (const float4*)(s_c + 512);
      float sa = 0.f, sm = 0.f;
      #pragma unroll
      for (int it = 0; it < 8; ++it) {
        float4 av = a4[gl + 16 * it], mv = m4[gl + 16 * it];
        sa += wU[it].x * av.x + wU[it].y * av.y + wU[it].z * av.z + wU[it].w * av.w;
        sm += wU[it].x * mv.x + wU[it].y * mv.y + wU[it].z * mv.z + wU[it].w * mv.w;
      }
      #pragma unroll
      for (int o = 8; o; o >>= 1) { sa += __shfl_xor(sa, o, 64); sm += __shfl_xor(sm, o, 64); }
      const float uA = sa, uM = sm;

      // contrib from register-resident G (pads: s_ar[100..111] == 0)
      float contrib = 0.f;
      #pragma unroll
      for (int k = 0; k < 7; ++k) contrib += s_ar[gl + 16 * k] * gr[k];
      contrib = rsum16(contrib);
      if (!gl) {
        float h = fmaxf(contrib + whv + preO_c + biasO, 0.f);
        if (ownHsel == 0) {
          a.out[(size_t)t * 512 + ownJ] = h;
          gstTag(cout + 1024 + ownJ, h, tagB + 1);
        } else if (ownHsel == 1) {
          gstTag(cout + ownJ, h, tagB + 1);
        } else {
          gstTag(cout + 512 + ownJ, h, tagB + 1);
        }
      }
      // G update (registers; reads s_awa/s_awm — safe until SYNC0(t+1))
      #pragma unroll
      for (int k = 0; k < 7; ++k) {
        int idx = gl + 16 * k;
        gr[k] = aw0 * gr[k] + aw1 * s_awa[idx] * uA + aw2 * s_awm[idx] * uM;
      }
    }
    // NO SYNC2: a wave can only pass the carry poll of step t+1 after every
    // wave (globally, incl. own block) executed its h'-publish, which is
    // program-order after all step-t reads of s_x/s_c/s_ar/s_awa/s_aw;
    // SYNC0(t+1) then fences the deferred G-update reads against phase-B
    // rewrites of s_awa/s_awm.

    // rotate the pipelined prefetch registers
    preA_c = preA_n;
    preO_c = preO_n;
  }
}

// ---------------- host ----------------
extern "C" void kernel_launch(void* const* d_in, const int* in_sizes, int n_in,
                              void* d_out, int out_size, void* d_ws, size_t ws_size,
                              hipStream_t stream) {
  const float* Xa    = (const float*)d_in[0];
  const float* Xm    = (const float*)d_in[1];
  const float* W_ca  = (const float*)d_in[2];  const float* b_ca  = (const float*)d_in[3];
  const float* W_cm  = (const float*)d_in[4];  const float* b_cm  = (const float*)d_in[5];
  const float* W_wp  = (const float*)d_in[6];  const float* b_wp  = (const float*)d_in[7];
  const float* W_wpa = (const float*)d_in[8];  const float* b_wpa = (const float*)d_in[9];
  const float* W_wpm = (const float*)d_in[10]; const float* b_wpm = (const float*)d_in[11];
  const float* W_rp  = (const float*)d_in[12]; const float* b_rp  = (const float*)d_in[13];
  const float* W_rh  = (const float*)d_in[14]; const float* b_rh  = (const float*)d_in[15];
  const float* W_rha = (const float*)d_in[16]; const float* b_rha = (const float*)d_in[17];
  const float* W_rhm = (const float*)d_in[18]; const float* b_rhm = (const float*)d_in[19];

  int nT = out_size / HS;   // 4096
  float* ws = (float*)d_ws;

  initK<<<dim3(64), dim3(256), 0, stream>>>(
      (unsigned long long*)(ws + OFF_CARRY),
      (unsigned long long*)(ws + OFF_BCAST));

  dim3 tb(32, 8);
  auto tg = [](int R, int C) { return dim3((C + 31) / 32, (R + 31) / 32); };
  transK<<<tg(1536, 100), tb, 0, stream>>>(W_rp,                       ws + OFF_TWrp,  1536, 100);
  transK<<<tg(1536, 3),   tb, 0, stream>>>(W_wp,                       ws + OFF_TWwp,  1536, 3);
  transK<<<tg(512, 100),  tb, 0, stream>>>(W_wpa,                      ws + OFF_TWwpa, 512, 100);
  transK<<<tg(512, 100),  tb, 0, stream>>>(W_wpm,                      ws + OFF_TWwpm, 512, 100);
  transK<<<tg(512, 512),  tb, 0, stream>>>(W_ca,                       ws + OFF_TWca,  512, 512);
  transK<<<tg(512, 512),  tb, 0, stream>>>(W_cm,                       ws + OFF_TWcm,  512, 512);
  transK<<<tg(512, 512),  tb, 0, stream>>>(W_rh  + 512 * 512,          ws + OFF_TWh0,  512, 512);
  transK<<<tg(512, 512),  tb, 0, stream>>>(W_rha + (size_t)2560 * 512, ws + OFF_TWh1,  512, 512);
  transK<<<tg(512, 512),  tb, 0, stream>>>(W_rhm + (size_t)2560 * 512, ws + OFF_TWh2,  512, 512);
  transK<<<tg(512, 512),  tb, 0, stream>>>(W_rh,                       ws + OFF_TWu0,  512, 512);
  transK<<<tg(512, 512),  tb, 0, stream>>>(W_rha + (size_t)2048 * 512, ws + OFF_TWu1,  512, 512);
  transK<<<tg(512, 512),  tb, 0, stream>>>(W_rhm + (size_t)2048 * 512, ws + OFF_TWu2,  512, 512);

  int tB = nT / 128;
  gemm128<<<dim3(4, tB), dim3(256), 0, stream>>>(Xa, W_ca + (size_t)512 * 512, ws + OFF_PAca);
  gemm128<<<dim3(4, tB), dim3(256), 0, stream>>>(Xm, W_cm + (size_t)512 * 512, ws + OFF_PMcm);
  gemm128<<<dim3(4, tB), dim3(256), 0, stream>>>(Xa, W_rha,                    ws + OFF_PArha);
  gemm128<<<dim3(4, tB), dim3(256), 0, stream>>>(Xm, W_rhm,                    ws + OFF_PMrhm);
  int tB64 = nT / 64;
  gemmK<<<dim3(2, tB64), dim3(256), 0, stream>>>(Xa, W_wpa + (size_t)512 * 100, ws + OFF_PAwpa, 100);
  gemmK<<<dim3(2, tB64), dim3(256), 0, stream>>>(Xm, W_wpm + (size_t)512 * 100, ws + OFF_PMwpm, 100);

  RArgs a;
  a.TWrp  = ws + OFF_TWrp;  a.TWwp  = ws + OFF_TWwp;
  a.TWwpa = ws + OFF_TWwpa; a.TWwpm = ws + OFF_TWwpm;
  a.TWca  = ws + OFF_TWca;  a.TWcm  = ws + OFF_TWcm;
  a.TWh0  = ws + OFF_TWh0;  a.TWh1  = ws + OFF_TWh1;  a.TWh2 = ws + OFF_TWh2;
  a.TWu0  = ws + OFF_TWu0;  a.TWu1  = ws + OFF_TWu1;  a.TWu2 = ws + OFF_TWu2;
  a.PAca  = ws + OFF_PAca;  a.PMcm  = ws + OFF_PMcm;
  a.PArha = ws + OFF_PArha; a.PMrhm = ws + OFF_PMrhm;
  a.PAwpa = ws + OFF_PAwpa; a.PMwpm = ws + OFF_PMwpm;
  a.b_ca = b_ca; a.b_cm = b_cm; a.b_wp = b_wp; a.b_wpa = b_wpa; a.b_wpm = b_wpm;
  a.b_rp = b_rp; a.b_rh = b_rh; a.b_rha = b_rha; a.b_rhm = b_rhm;
  a.carryT = (unsigned long long*)(ws + OFF_CARRY);
  a.bcast  = (unsigned long long*)(ws + OFF_BCAST);
  a.out    = (float*)d_out;
  a.nT     = nT;

  recurK<<<dim3(GBLK), dim3(TPB), 0, stream>>>(a);
}